// Round 4
// baseline (46.533 us; speedup 1.0000x reference)
//
#include <hip/hip_runtime.h>
#include <hip/hip_bf16.h>

// y[b,i] = out[b,i] if lower[i] <= (out[b,i] - out[b,(i-1)%N]) <= upper[i] else 0
// where out = NaN/Inf-sanitized input, lower/upper = mean_grad -/+ k*sqrt(var_grad).
//
// Round-4: column-tiled traversal. Each thread owns 4 fixed columns; band
// (lo/hi) is computed ONCE into registers and reused across 16 rows. This
// cuts logical load traffic from 5 VMEM instr / float4 (in, prev, mean, var,
// store) to 2 (in, store): bands were 268 MB of redundant L1/L2 reads.
// prev element comes from __shfl_up of the neighbor lane's sanitized .w
// (lane 0 of each wave patches with one scalar load). nt stores kept (R3 +8%).

typedef float f32x4 __attribute__((ext_vector_type(4)));

__device__ __forceinline__ float sanitize(float x) {
    unsigned u = __float_as_uint(x);
    return ((u & 0x7f800000u) == 0x7f800000u) ? 0.0f : x;
}

#define RPB 16   // rows per block
#define TPB 256  // threads per block

__global__ __launch_bounds__(TPB) void correction_kernel(
    const float* __restrict__ in,
    const float* __restrict__ mean_grad,
    const float* __restrict__ var_grad,
    const int* __restrict__ kptr,
    float* __restrict__ y,
    int N, int colTiles)
{
    const int ct = blockIdx.x % colTiles;          // column tile (fastest -> contiguous writes)
    const int rt = blockIdx.x / colTiles;          // row tile
    const int c  = ct * (TPB * 4) + threadIdx.x * 4;
    const int lane = threadIdx.x & 63;
    const int pc = (c == 0) ? (N - 1) : (c - 1);   // circular prev column for lane 0
    const float kf = (float)(*kptr);

    // Bands into registers, once per block.
    f32x4 m  = *reinterpret_cast<const f32x4*>(mean_grad + c);
    f32x4 vr = *reinterpret_cast<const f32x4*>(var_grad + c);
    // k=4 is a power of two: kf*sqrtf() exact; lo/hi single-rounded == NumPy.
    f32x4 lo, hi;
    lo.x = m.x - kf * sqrtf(vr.x);  hi.x = m.x + kf * sqrtf(vr.x);
    lo.y = m.y - kf * sqrtf(vr.y);  hi.y = m.y + kf * sqrtf(vr.y);
    lo.z = m.z - kf * sqrtf(vr.z);  hi.z = m.z + kf * sqrtf(vr.z);
    lo.w = m.w - kf * sqrtf(vr.w);  hi.w = m.w + kf * sqrtf(vr.w);

    const int r0 = rt * RPB;
    #pragma unroll 4
    for (int r = r0; r < r0 + RPB; ++r) {
        const float* __restrict__ rp = in + (size_t)r * (size_t)N;
        f32x4 x = *reinterpret_cast<const f32x4*>(rp + c);

        float s0 = sanitize(x.x);
        float s1 = sanitize(x.y);
        float s2 = sanitize(x.z);
        float s3 = sanitize(x.w);

        // prev for element c is column c-1 = neighbor lane's .w (sanitized).
        float sp = __shfl_up(s3, 1);
        if (lane == 0) sp = sanitize(rp[pc]);

        float d0 = s0 - sp;
        float d1 = s1 - s0;
        float d2 = s2 - s1;
        float d3 = s3 - s2;

        f32x4 out;
        out.x = (d0 < lo.x || d0 > hi.x) ? 0.0f : s0;
        out.y = (d1 < lo.y || d1 > hi.y) ? 0.0f : s1;
        out.z = (d2 < lo.z || d2 > hi.z) ? 0.0f : s2;
        out.w = (d3 < lo.w || d3 > hi.w) ? 0.0f : s3;

        __builtin_nontemporal_store(out,
            reinterpret_cast<f32x4*>(y + (size_t)r * (size_t)N + c));
    }
}

extern "C" void kernel_launch(void* const* d_in, const int* in_sizes, int n_in,
                              void* d_out, int out_size, void* d_ws, size_t ws_size,
                              hipStream_t stream) {
    const float* in        = (const float*)d_in[0];
    const float* mean_grad = (const float*)d_in[1];
    const float* var_grad  = (const float*)d_in[2];
    const int*   kptr      = (const int*)d_in[3];
    float* y = (float*)d_out;

    const int N = in_sizes[1];              // 8192
    const int B = in_sizes[0] / N;          // 4096

    const int colTiles = N / (TPB * 4);     // 8
    const int rowTiles = B / RPB;           // 256
    dim3 grid(colTiles * rowTiles);         // 2048 blocks
    dim3 block(TPB);
    correction_kernel<<<grid, block, 0, stream>>>(in, mean_grad, var_grad, kptr, y, N, colTiles);
}

// Round 5
// 44.972 us; speedup vs baseline: 1.0347x; 1.0347x over previous
//
#include <hip/hip_runtime.h>
#include <hip/hip_bf16.h>

// y[b,i] = out[b,i] if lower[i] <= (out[b,i] - out[b,(i-1)%N]) <= upper[i] else 0
// where out = NaN/Inf-sanitized input, lower/upper = mean_grad -/+ k*sqrt(var_grad).
//
// Round-5: R3 structure (row-per-block; it beat R4's column-tiled 44.8 vs
// 46.5) + stores with FULL cache-bypass policy bits (sc0 sc1 nt) via inline
// asm. R4 evidence: FETCH == half the input => MALL write-allocates despite
// plain `nt`, evicting input. If sc1 stops MALL allocation, input becomes
// fully L3-resident -> FETCH ~0, time -> write-stream-limited ~20-30 us.

typedef float f32x4 __attribute__((ext_vector_type(4)));

__device__ __forceinline__ float sanitize(float x) {
    // NaN or Inf  <=>  exponent bits all ones
    unsigned u = __float_as_uint(x);
    return ((u & 0x7f800000u) == 0x7f800000u) ? 0.0f : x;
}

__device__ __forceinline__ void store_bypass(float* p, f32x4 v) {
    // sc0 sc1 nt: non-temporal + system-scope -> no allocation at any level.
    asm volatile("global_store_dwordx4 %0, %1, off sc0 sc1 nt"
                 :: "v"(p), "v"(v) : "memory");
}

__global__ __launch_bounds__(256) void correction_kernel(
    const float* __restrict__ in,
    const float* __restrict__ mean_grad,
    const float* __restrict__ var_grad,
    const int* __restrict__ kptr,
    float* __restrict__ y,
    int N)
{
    const int row = blockIdx.x;
    const float kf = (float)(*kptr);   // scalar load, broadcast
    const float* __restrict__ rp = in + (size_t)row * (size_t)N;
    float* __restrict__ ro = y + (size_t)row * (size_t)N;
    const int vec_per_row = N >> 2;

    for (int v = threadIdx.x; v < vec_per_row; v += blockDim.x) {
        const int i = v << 2;
        f32x4 x = *reinterpret_cast<const f32x4*>(rp + i);
        float prev = rp[(i == 0) ? (N - 1) : (i - 1)];   // circular, L1-hit

        float s0 = sanitize(x.x);
        float s1 = sanitize(x.y);
        float s2 = sanitize(x.z);
        float s3 = sanitize(x.w);
        float sp = sanitize(prev);

        f32x4 m  = *reinterpret_cast<const f32x4*>(mean_grad + i);
        f32x4 vr = *reinterpret_cast<const f32x4*>(var_grad + i);

        // k=4 is a power of two: kf*sqrtf() is exact after the correctly
        // rounded sqrt, so lo/hi match NumPy bit-for-bit (single rounding).
        float t0 = kf * sqrtf(vr.x);
        float t1 = kf * sqrtf(vr.y);
        float t2 = kf * sqrtf(vr.z);
        float t3 = kf * sqrtf(vr.w);

        float d0 = s0 - sp;
        float d1 = s1 - s0;
        float d2 = s2 - s1;
        float d3 = s3 - s2;

        f32x4 r;
        r.x = (d0 < m.x - t0 || d0 > m.x + t0) ? 0.0f : s0;
        r.y = (d1 < m.y - t1 || d1 > m.y + t1) ? 0.0f : s1;
        r.z = (d2 < m.z - t2 || d2 > m.z + t2) ? 0.0f : s2;
        r.w = (d3 < m.w - t3 || d3 > m.w + t3) ? 0.0f : s3;

        store_bypass(ro + i, r);
    }
}

extern "C" void kernel_launch(void* const* d_in, const int* in_sizes, int n_in,
                              void* d_out, int out_size, void* d_ws, size_t ws_size,
                              hipStream_t stream) {
    const float* in        = (const float*)d_in[0];
    const float* mean_grad = (const float*)d_in[1];
    const float* var_grad  = (const float*)d_in[2];
    const int*   kptr      = (const int*)d_in[3];
    float* y = (float*)d_out;

    const int N = in_sizes[1];              // 8192
    const int B = in_sizes[0] / N;          // 4096

    dim3 grid(B);
    dim3 block(256);
    correction_kernel<<<grid, block, 0, stream>>>(in, mean_grad, var_grad, kptr, y, N);
}